// Round 1
// baseline (439.132 us; speedup 1.0000x reference)
//
#include <hip/hip_runtime.h>
#include <math.h>

#define H 1024
#define L 128
#define V 50257
#define NB6 2048   // blocks for vocab matvec

// ws layout (float offsets)
#define WS_AL    0                       // 128  attn logits
#define WS_WATT  128                     // 1024 with_attention
#define WS_RNN   (128+1024)              // 1024 rnn_in
#define WS_GX    (128+2048)              // 3072
#define WS_GH    (128+2048+3072)         // 3072
#define WS_HNEW  (128+2048+6144)         // 1024
#define WS_PM    (128+2048+6144+1024)    // NB6 partial max
#define WS_PS    (WS_PM + NB6)           // NB6 partial sum
#define WS_LSE   (WS_PS + NB6)           // 1

__device__ __forceinline__ float wred(float v) {
    v += __shfl_down(v, 32);
    v += __shfl_down(v, 16);
    v += __shfl_down(v, 8);
    v += __shfl_down(v, 4);
    v += __shfl_down(v, 2);
    v += __shfl_down(v, 1);
    return v;
}

// K1: attn logits[l] = dot(cat(emb_row, h0), attn_W[l,:]) + attn_b[l]
// 32 blocks x 256 -> 128 waves, one wave per l
__global__ __launch_bounds__(256) void k_attn_logits(
        const float* __restrict__ emb, const int* __restrict__ x,
        const float* __restrict__ hid, const float* __restrict__ attn_W,
        const float* __restrict__ attn_b, float* __restrict__ ws) {
    int wave = blockIdx.x * 4 + (threadIdx.x >> 6);
    int lane = threadIdx.x & 63;
    const float* er = emb + (size_t)x[0] * H;
    const float* w  = attn_W + (size_t)wave * (2 * H);
    float acc = 0.f;
    #pragma unroll
    for (int k = 0; k < 8; ++k) {
        int j = (k * 64 + lane) * 4;
        float4 wv = *(const float4*)(w + j);
        const float* src = (j < H) ? (er + j) : (hid + (j - H));
        float4 cv = *(const float4*)src;
        acc += wv.x * cv.x + wv.y * cv.y + wv.z * cv.z + wv.w * cv.w;
    }
    acc = wred(acc);
    if (lane == 0) ws[WS_AL + wave] = acc + attn_b[wave];
}

// K2: softmax over 128 (redundant per block) + with_attention[h]
// 4 blocks x 256, thread h = blockIdx*256+t
__global__ __launch_bounds__(256) void k_attn_apply(
        const float* __restrict__ enc, float* __restrict__ ws,
        float* __restrict__ out) {
    __shared__ float sl[L];
    __shared__ float swt[L];
    int t = threadIdx.x;
    if (t < L) sl[t] = ws[WS_AL + t];
    __syncthreads();
    float m = -1e30f;
    #pragma unroll 8
    for (int i = 0; i < L; ++i) m = fmaxf(m, sl[i]);
    float s = 0.f;
    #pragma unroll 4
    for (int i = 0; i < L; ++i) s += expf(sl[i] - m);
    float inv = 1.f / s;
    if (t < L) swt[t] = expf(sl[t] - m) * inv;
    __syncthreads();
    int h = blockIdx.x * 256 + t;
    float acc = 0.f;
    #pragma unroll 8
    for (int l = 0; l < L; ++l) acc += swt[l] * enc[l * H + h];
    ws[WS_WATT + h] = acc;
    if (blockIdx.x == 0 && t < L) out[V + H + t] = swt[t];
}

// K3: rnn_in (1024 waves, dot 2048) + gh (3072 waves, dot 1024)
// 1024 blocks x 256 -> 4096 waves
__global__ __launch_bounds__(256) void k_rnn_gh(
        const float* __restrict__ emb, const int* __restrict__ x,
        const float* __restrict__ hid, const float* __restrict__ comb_W,
        const float* __restrict__ comb_b, const float* __restrict__ W_hh,
        const float* __restrict__ b_hh, float* __restrict__ ws) {
    int wave = blockIdx.x * 4 + (threadIdx.x >> 6);
    int lane = threadIdx.x & 63;
    if (wave < H) {
        const float* er = emb + (size_t)x[0] * H;
        const float* w  = comb_W + (size_t)wave * (2 * H);
        const float* watt = ws + WS_WATT;
        float acc = 0.f;
        #pragma unroll
        for (int k = 0; k < 8; ++k) {
            int j = (k * 64 + lane) * 4;
            float4 wv = *(const float4*)(w + j);
            const float* src = (j < H) ? (er + j) : (watt + (j - H));
            float4 cv = *(const float4*)src;
            acc += wv.x * cv.x + wv.y * cv.y + wv.z * cv.z + wv.w * cv.w;
        }
        acc = wred(acc);
        if (lane == 0) ws[WS_RNN + wave] = fmaxf(acc + comb_b[wave], 0.f);
    } else {
        int r = wave - H;   // 0..3071
        const float* w = W_hh + (size_t)r * H;
        float acc = 0.f;
        #pragma unroll
        for (int k = 0; k < 4; ++k) {
            int j = (k * 64 + lane) * 4;
            float4 wv = *(const float4*)(w + j);
            float4 hv = *(const float4*)(hid + j);
            acc += wv.x * hv.x + wv.y * hv.y + wv.z * hv.z + wv.w * hv.w;
        }
        acc = wred(acc);
        if (lane == 0) ws[WS_GH + r] = acc + b_hh[r];
    }
}

// K4: gx[r] = dot(rnn_in, W_ih[r,:]) + b_ih[r]; 768 blocks -> 3072 waves
__global__ __launch_bounds__(256) void k_gx(
        const float* __restrict__ W_ih, const float* __restrict__ b_ih,
        float* __restrict__ ws) {
    int r = blockIdx.x * 4 + (threadIdx.x >> 6);
    int lane = threadIdx.x & 63;
    const float* w = W_ih + (size_t)r * H;
    const float* rn = ws + WS_RNN;
    float acc = 0.f;
    #pragma unroll
    for (int k = 0; k < 4; ++k) {
        int j = (k * 64 + lane) * 4;
        float4 wv = *(const float4*)(w + j);
        float4 rv = *(const float4*)(rn + j);
        acc += wv.x * rv.x + wv.y * rv.y + wv.z * rv.z + wv.w * rv.w;
    }
    acc = wred(acc);
    if (lane == 0) ws[WS_GX + r] = acc + b_ih[r];
}

// K5: GRU gates elementwise; 4 blocks x 256
__global__ __launch_bounds__(256) void k_gru(
        const float* __restrict__ hid, float* __restrict__ ws,
        float* __restrict__ out) {
    int h = blockIdx.x * 256 + threadIdx.x;
    const float* gx = ws + WS_GX;
    const float* gh = ws + WS_GH;
    float r = 1.f / (1.f + expf(-(gx[h] + gh[h])));
    float z = 1.f / (1.f + expf(-(gx[H + h] + gh[H + h])));
    float n = tanhf(gx[2 * H + h] + r * gh[2 * H + h]);
    float hn = (1.f - z) * n + z * hid[h];
    ws[WS_HNEW + h] = hn;
    out[V + h] = hn;
}

// K6: vocab matvec, wave-per-row grid-stride + fused per-block online lse partials
__global__ __launch_bounds__(256) void k_logits(
        const float* __restrict__ out_W, const float* __restrict__ out_b,
        float* __restrict__ ws, float* __restrict__ out) {
    int wid = threadIdx.x >> 6;
    int lane = threadIdx.x & 63;
    int gw = blockIdx.x * 4 + wid;
    const float* hn = ws + WS_HNEW;
    float m = -INFINITY, s = 0.f;
    for (int row = gw; row < V; row += NB6 * 4) {
        const float* w = out_W + (size_t)row * H;
        float acc = 0.f;
        #pragma unroll
        for (int k = 0; k < 4; ++k) {
            int j = (k * 64 + lane) * 4;
            float4 wv = *(const float4*)(w + j);
            float4 hv = *(const float4*)(hn + j);
            acc += wv.x * hv.x + wv.y * hv.y + wv.z * hv.z + wv.w * hv.w;
        }
        acc = wred(acc);
        if (lane == 0) {
            float logit = acc + out_b[row];
            out[row] = logit;
            if (logit > m) { s = s * expf(m - logit) + 1.f; m = logit; }
            else           { s += expf(logit - m); }
        }
    }
    __shared__ float sm[4], ss[4];
    if (lane == 0) { sm[wid] = m; ss[wid] = s; }
    __syncthreads();
    if (threadIdx.x == 0) {
        float M = fmaxf(fmaxf(sm[0], sm[1]), fmaxf(sm[2], sm[3]));
        float S = ss[0] * expf(sm[0] - M) + ss[1] * expf(sm[1] - M)
                + ss[2] * expf(sm[2] - M) + ss[3] * expf(sm[3] - M);
        ws[WS_PM + blockIdx.x] = M;
        ws[WS_PS + blockIdx.x] = S;
    }
}

// K7: reduce NB6 (m,s) partials -> lse; 1 block x 256
__global__ __launch_bounds__(256) void k_lse(float* __restrict__ ws) {
    __shared__ float sm[256], ss[256];
    int t = threadIdx.x;
    float m = -INFINITY, s = 0.f;
    for (int i = t; i < NB6; i += 256) {
        float mi = ws[WS_PM + i], si = ws[WS_PS + i];
        float M = fmaxf(m, mi);
        s = s * expf(m - M) + si * expf(mi - M);
        m = M;
    }
    sm[t] = m; ss[t] = s;
    __syncthreads();
    for (int off = 128; off > 0; off >>= 1) {
        if (t < off) {
            float m2 = sm[t + off], s2 = ss[t + off];
            float M = fmaxf(sm[t], m2);
            ss[t] = ss[t] * expf(sm[t] - M) + s2 * expf(m2 - M);
            sm[t] = M;
        }
        __syncthreads();
    }
    if (t == 0) ws[WS_LSE] = sm[0] + logf(ss[0]);
}

// K8: logp = logit - lse (in place on d_out)
__global__ __launch_bounds__(256) void k_finalize(
        float* __restrict__ out, const float* __restrict__ ws) {
    int i = blockIdx.x * 256 + threadIdx.x;
    if (i < V) out[i] -= ws[WS_LSE];
}

extern "C" void kernel_launch(void* const* d_in, const int* in_sizes, int n_in,
                              void* d_out, int out_size, void* d_ws, size_t ws_size,
                              hipStream_t stream) {
    const int*   x      = (const int*)  d_in[0];
    const float* hidden = (const float*)d_in[1];
    const float* enc    = (const float*)d_in[2];
    const float* emb    = (const float*)d_in[3];
    const float* attn_W = (const float*)d_in[4];
    const float* attn_b = (const float*)d_in[5];
    const float* comb_W = (const float*)d_in[6];
    const float* comb_b = (const float*)d_in[7];
    const float* W_ih   = (const float*)d_in[8];
    const float* W_hh   = (const float*)d_in[9];
    const float* b_ih   = (const float*)d_in[10];
    const float* b_hh   = (const float*)d_in[11];
    const float* out_W  = (const float*)d_in[12];
    const float* out_b  = (const float*)d_in[13];
    float* out = (float*)d_out;
    float* ws  = (float*)d_ws;

    k_attn_logits<<<32, 256, 0, stream>>>(emb, x, hidden, attn_W, attn_b, ws);
    k_attn_apply <<<4, 256, 0, stream>>>(enc, ws, out);
    k_rnn_gh     <<<1024, 256, 0, stream>>>(emb, x, hidden, comb_W, comb_b, W_hh, b_hh, ws);
    k_gx         <<<768, 256, 0, stream>>>(W_ih, b_ih, ws);
    k_gru        <<<4, 256, 0, stream>>>(hidden, ws, out);
    k_logits     <<<NB6, 256, 0, stream>>>(out_W, out_b, ws, out);
    k_lse        <<<1, 256, 0, stream>>>(ws);
    k_finalize   <<<(V + 255) / 256, 256, 0, stream>>>(out, ws);
}

// Round 2
// 432.621 us; speedup vs baseline: 1.0151x; 1.0151x over previous
//
#include <hip/hip_runtime.h>
#include <math.h>

#define H 1024
#define L 128
#define V 50257
#define NB6 2048   // blocks for vocab matvec

// ws layout (float offsets)
#define WS_AL    0                       // 128  attn logits
#define WS_WATT  128                     // 1024 with_attention
#define WS_RNN   (128+1024)              // 1024 rnn_in
#define WS_GX    (128+2048)              // 3072
#define WS_GH    (128+2048+3072)         // 3072
#define WS_PM    (128+2048+6144)         // NB6 partial max
#define WS_PS    (WS_PM + NB6)           // NB6 partial sum

__device__ __forceinline__ float wred(float v) {
    v += __shfl_down(v, 32);
    v += __shfl_down(v, 16);
    v += __shfl_down(v, 8);
    v += __shfl_down(v, 4);
    v += __shfl_down(v, 2);
    v += __shfl_down(v, 1);
    return v;
}

// K1: FUSED attn logits (waves 0..127) + gh = W_hh*h0 + b_hh (waves 128..3199)
// 800 blocks x 256 -> 3200 waves
__global__ __launch_bounds__(256) void k_attn_gh(
        const float* __restrict__ emb, const int* __restrict__ x,
        const float* __restrict__ hid, const float* __restrict__ attn_W,
        const float* __restrict__ attn_b, const float* __restrict__ W_hh,
        const float* __restrict__ b_hh, float* __restrict__ ws) {
    int w = blockIdx.x * 4 + (threadIdx.x >> 6);
    int lane = threadIdx.x & 63;
    if (w < L) {
        const float* er = emb + (size_t)x[0] * H;
        const float* aw = attn_W + (size_t)w * (2 * H);
        float acc = 0.f;
        #pragma unroll
        for (int k = 0; k < 8; ++k) {
            int j = (k * 64 + lane) * 4;
            float4 wv = *(const float4*)(aw + j);
            const float* src = (j < H) ? (er + j) : (hid + (j - H));
            float4 cv = *(const float4*)src;
            acc += wv.x * cv.x + wv.y * cv.y + wv.z * cv.z + wv.w * cv.w;
        }
        acc = wred(acc);
        if (lane == 0) ws[WS_AL + w] = acc + attn_b[w];
    } else {
        int r = w - L;   // 0..3071
        const float* wr = W_hh + (size_t)r * H;
        float acc = 0.f;
        #pragma unroll
        for (int k = 0; k < 4; ++k) {
            int j = (k * 64 + lane) * 4;
            float4 wv = *(const float4*)(wr + j);
            float4 hv = *(const float4*)(hid + j);
            acc += wv.x * hv.x + wv.y * hv.y + wv.z * hv.z + wv.w * hv.w;
        }
        acc = wred(acc);
        if (lane == 0) ws[WS_GH + r] = acc + b_hh[r];
    }
}

// K2: softmax over 128 (redundant per block) + with_attention
// 16 blocks x 256; block covers 64 columns, 4 L-chunks per column
__global__ __launch_bounds__(256) void k_attn_apply(
        const float* __restrict__ enc, float* __restrict__ ws,
        float* __restrict__ out) {
    __shared__ float sl[L];
    __shared__ float swt[L];
    __shared__ float part[4][64];
    int t = threadIdx.x;
    if (t < L) sl[t] = ws[WS_AL + t];
    __syncthreads();
    float m = -1e30f;
    #pragma unroll 8
    for (int i = 0; i < L; ++i) m = fmaxf(m, sl[i]);
    float s = 0.f;
    #pragma unroll 4
    for (int i = 0; i < L; ++i) s += expf(sl[i] - m);
    float inv = 1.f / s;
    if (t < L) swt[t] = expf(sl[t] - m) * inv;
    __syncthreads();
    int col = t & 63, q = t >> 6;
    int h = blockIdx.x * 64 + col;
    float acc = 0.f;
    #pragma unroll 8
    for (int l = q * 32; l < q * 32 + 32; ++l) acc += swt[l] * enc[l * H + h];
    part[q][col] = acc;
    __syncthreads();
    if (q == 0)
        ws[WS_WATT + h] = part[0][col] + part[1][col] + part[2][col] + part[3][col];
    if (blockIdx.x == 0 && t < L) out[V + H + t] = swt[t];
}

// K3: rnn_in = relu(comb_W @ cat(emb_row, watt) + comb_b); 256 blocks -> 1024 waves
__global__ __launch_bounds__(256) void k_rnn_in(
        const float* __restrict__ emb, const int* __restrict__ x,
        const float* __restrict__ comb_W, const float* __restrict__ comb_b,
        float* __restrict__ ws) {
    int wave = blockIdx.x * 4 + (threadIdx.x >> 6);
    int lane = threadIdx.x & 63;
    const float* er = emb + (size_t)x[0] * H;
    const float* w  = comb_W + (size_t)wave * (2 * H);
    const float* watt = ws + WS_WATT;
    float acc = 0.f;
    #pragma unroll
    for (int k = 0; k < 8; ++k) {
        int j = (k * 64 + lane) * 4;
        float4 wv = *(const float4*)(w + j);
        const float* src = (j < H) ? (er + j) : (watt + (j - H));
        float4 cv = *(const float4*)src;
        acc += wv.x * cv.x + wv.y * cv.y + wv.z * cv.z + wv.w * cv.w;
    }
    acc = wred(acc);
    if (lane == 0) ws[WS_RNN + wave] = fmaxf(acc + comb_b[wave], 0.f);
}

// K4: gx[r] = dot(rnn_in, W_ih[r,:]) + b_ih[r]; 768 blocks -> 3072 waves
__global__ __launch_bounds__(256) void k_gx(
        const float* __restrict__ W_ih, const float* __restrict__ b_ih,
        float* __restrict__ ws) {
    int r = blockIdx.x * 4 + (threadIdx.x >> 6);
    int lane = threadIdx.x & 63;
    const float* w = W_ih + (size_t)r * H;
    const float* rn = ws + WS_RNN;
    float acc = 0.f;
    #pragma unroll
    for (int k = 0; k < 4; ++k) {
        int j = (k * 64 + lane) * 4;
        float4 wv = *(const float4*)(w + j);
        float4 rv = *(const float4*)(rn + j);
        acc += wv.x * rv.x + wv.y * rv.y + wv.z * rv.z + wv.w * rv.w;
    }
    acc = wred(acc);
    if (lane == 0) ws[WS_GX + r] = acc + b_ih[r];
}

// K5: vocab matvec with per-block GRU prologue (h_new rebuilt into LDS)
// + fused per-block online lse partials
__global__ __launch_bounds__(256) void k_logits(
        const float* __restrict__ out_W, const float* __restrict__ out_b,
        const float* __restrict__ hid, float* __restrict__ ws,
        float* __restrict__ out) {
    __shared__ float sh[H];
    int t = threadIdx.x;
    const float* gx = ws + WS_GX;
    const float* gh = ws + WS_GH;
    // redundant GRU: ~28KB of L2-resident reads per block, 4 elems/thread
    #pragma unroll
    for (int i = t; i < H; i += 256) {
        float r = 1.f / (1.f + expf(-(gx[i] + gh[i])));
        float z = 1.f / (1.f + expf(-(gx[H + i] + gh[H + i])));
        float n = tanhf(gx[2 * H + i] + r * gh[2 * H + i]);
        float hn = (1.f - z) * n + z * hid[i];
        sh[i] = hn;
        if (blockIdx.x == 0) out[V + i] = hn;
    }
    __syncthreads();

    int wid = t >> 6;
    int lane = t & 63;
    int gw = blockIdx.x * 4 + wid;
    float m = -INFINITY, s = 0.f;
    for (int row = gw; row < V; row += NB6 * 4) {
        const float* w = out_W + (size_t)row * H;
        float acc = 0.f;
        #pragma unroll
        for (int k = 0; k < 4; ++k) {
            int j = (k * 64 + lane) * 4;
            float4 wv = *(const float4*)(w + j);
            float4 hv = *(const float4*)(sh + j);
            acc += wv.x * hv.x + wv.y * hv.y + wv.z * hv.z + wv.w * hv.w;
        }
        acc = wred(acc);
        if (lane == 0) {
            float logit = acc + out_b[row];
            out[row] = logit;
            if (logit > m) { s = s * expf(m - logit) + 1.f; m = logit; }
            else           { s += expf(logit - m); }
        }
    }
    __shared__ float sm[4], ss[4];
    if (lane == 0) { sm[wid] = m; ss[wid] = s; }
    __syncthreads();
    if (t == 0) {
        float M = fmaxf(fmaxf(sm[0], sm[1]), fmaxf(sm[2], sm[3]));
        float S = ss[0] * expf(sm[0] - M) + ss[1] * expf(sm[1] - M)
                + ss[2] * expf(sm[2] - M) + ss[3] * expf(sm[3] - M);
        ws[WS_PM + blockIdx.x] = M;
        ws[WS_PS + blockIdx.x] = S;
    }
}

// K6: finalize with per-block redundant lse reduce (16KB L2 reads/block)
__global__ __launch_bounds__(256) void k_finalize(
        float* __restrict__ out, const float* __restrict__ ws) {
    __shared__ float sm[256], ss[256];
    int t = threadIdx.x;
    float m = -INFINITY, s = 0.f;
    for (int i = t; i < NB6; i += 256) {
        float mi = ws[WS_PM + i], si = ws[WS_PS + i];
        float M = fmaxf(m, mi);
        s = s * expf(m - M) + si * expf(mi - M);
        m = M;
    }
    sm[t] = m; ss[t] = s;
    __syncthreads();
    for (int off = 128; off > 0; off >>= 1) {
        if (t < off) {
            float m2 = sm[t + off], s2 = ss[t + off];
            float M = fmaxf(sm[t], m2);
            ss[t] = ss[t] * expf(sm[t] - M) + s2 * expf(m2 - M);
            sm[t] = M;
        }
        __syncthreads();
    }
    float lse = sm[0] + logf(ss[0]);
    int i = blockIdx.x * 256 + t;
    if (i < V) out[i] -= lse;
}

extern "C" void kernel_launch(void* const* d_in, const int* in_sizes, int n_in,
                              void* d_out, int out_size, void* d_ws, size_t ws_size,
                              hipStream_t stream) {
    const int*   x      = (const int*)  d_in[0];
    const float* hidden = (const float*)d_in[1];
    const float* enc    = (const float*)d_in[2];
    const float* emb    = (const float*)d_in[3];
    const float* attn_W = (const float*)d_in[4];
    const float* attn_b = (const float*)d_in[5];
    const float* comb_W = (const float*)d_in[6];
    const float* comb_b = (const float*)d_in[7];
    const float* W_ih   = (const float*)d_in[8];
    const float* W_hh   = (const float*)d_in[9];
    const float* b_ih   = (const float*)d_in[10];
    const float* b_hh   = (const float*)d_in[11];
    const float* out_W  = (const float*)d_in[12];
    const float* out_b  = (const float*)d_in[13];
    float* out = (float*)d_out;
    float* ws  = (float*)d_ws;

    k_attn_gh    <<<800, 256, 0, stream>>>(emb, x, hidden, attn_W, attn_b, W_hh, b_hh, ws);
    k_attn_apply <<<16, 256, 0, stream>>>(enc, ws, out);
    k_rnn_in     <<<256, 256, 0, stream>>>(emb, x, comb_W, comb_b, ws);
    k_gx         <<<768, 256, 0, stream>>>(W_ih, b_ih, ws);
    k_logits     <<<NB6, 256, 0, stream>>>(out_W, out_b, hidden, ws, out);
    k_finalize   <<<(V + 255) / 256, 256, 0, stream>>>(out, ws);
}